// Round 1
// baseline (277.097 us; speedup 1.0000x reference)
//
#include <hip/hip_runtime.h>
#include <math.h>

#define NA 32768

// ---------------------------------------------------------------------------
// Setup kernel: fold wpost + scales into gw2/gb2.
//   W2p[k, e] = sum_w gw2[k, idx, u, w] * wpost_{lo(idx)}[pos(idx)*16 + w] * scale_lo
//   (e = idx*16 + u, k = 0..63)
// scale_lo = (1/sqrt(MUL)) / sqrt(U_lo) = 0.25 / sqrt({48,32,64})
// ---------------------------------------------------------------------------
__global__ void setup_kernel(const float* __restrict__ gw2, const float* __restrict__ gb2,
                             const float* __restrict__ wpost0, const float* __restrict__ wpost1,
                             const float* __restrict__ wpost2,
                             float* __restrict__ w2p, float* __restrict__ b2p) {
    const int LO[9]  = {0, 2, 0, 1, 2, 2, 0, 1, 2};
    const int POS[9] = {0, 0, 1, 0, 1, 2, 2, 1, 3};
    const float SCALE[3] = {0.036084391824351615f,   // 1/(4*sqrt(48))
                            0.04419417382415922f,    // 1/(4*sqrt(32))
                            0.03125f};               // 1/(4*sqrt(64))
    int t = blockIdx.x * 256 + threadIdx.x;
    if (t >= 64 * 144) return;
    int e = t % 144, k = t / 144;
    int idx = e >> 4, u = e & 15;
    int lo = LO[idx], pos = POS[idx];
    const float* wp = (lo == 0) ? wpost0 : (lo == 1) ? wpost1 : wpost2;
    const float* wv = wp + pos * 16;
    float scale = SCALE[lo];

    const float* gsrc = gw2 + (size_t)k * 2304 + idx * 256 + u * 16;
    float s = 0.f;
#pragma unroll
    for (int w = 0; w < 16; ++w) s = fmaf(gsrc[w], wv[w], s);
    w2p[t] = s * scale;

    if (t < 144) {  // k == 0 here; same (idx,u,wv)
        const float* bsrc = gb2 + idx * 256 + u * 16;
        float sb = 0.f;
#pragma unroll
        for (int w = 0; w < 16; ++w) sb = fmaf(bsrc[w], wv[w], sb);
        b2p[t] = sb * scale;
    }
}

// ---------------------------------------------------------------------------
// Main kernel: 4 waves / block, one wave per atom.
// ---------------------------------------------------------------------------
__global__ __launch_bounds__(256) void csc_kernel(
    const float* __restrict__ x_scalar, const float* __restrict__ x_sph,
    const float* __restrict__ w_pre0, const float* __restrict__ w_pre1,
    const float* __restrict__ w_pre2,
    const float* __restrict__ gw1, const float* __restrict__ gb1,
    const float* __restrict__ w2p, const float* __restrict__ b2p,
    float* __restrict__ out)
{
    __shared__ float shid[4][64];
    __shared__ float sh[4][144];   // [0:16) h0 | [16:64) h1 (v*3+m) | [64:144) h2 (v*5+m)
    __shared__ float sG[4][144];   // idx*16+u

    const int lane = threadIdx.x & 63;
    const int wv   = threadIdx.x >> 6;
    const int n    = blockIdx.x * 4 + wv;

    const float* xs = x_scalar + (size_t)n * 128;
    const float* xq = x_sph    + (size_t)n * 480;

    // ---- hid[k] = silu(x_scalar . gw1[:,k] + gb1[k]), lane = k ----
    {
        float acc = gb1[lane];
#pragma unroll 8
        for (int u = 0; u < 128; ++u) acc = fmaf(xs[u], gw1[u * 64 + lane], acc);
        shid[wv][lane] = acc / (1.f + __expf(-acc));
    }

    // ---- h values (144 of them) ----
    if (lane < 16) {
        float a0 = 0.f;
#pragma unroll 8
        for (int u = 0; u < 128; ++u) a0 = fmaf(xq[u], w_pre0[u * 16 + lane], a0);
        sh[wv][lane] = a0 * 0.08838834764831845f;           // 1/sqrt(128)
    } else {
        int f = lane - 16, v = f / 3, m = f - 3 * v;
        float a1 = 0.f;
#pragma unroll 8
        for (int u = 0; u < 64; ++u) a1 = fmaf(xq[128 + u * 3 + m], w_pre1[u * 16 + v], a1);
        sh[wv][lane] = a1 * 0.125f;                         // 1/sqrt(64)
    }
    {
        int v = lane / 5, m = lane - 5 * v;
        float a2 = 0.f;
#pragma unroll 8
        for (int u = 0; u < 32; ++u) a2 = fmaf(xq[320 + u * 5 + m], w_pre2[u * 16 + v], a2);
        sh[wv][64 + lane] = a2 * 0.17677669529663687f;      // 1/sqrt(32)
        if (lane < 16) {
            int f = 64 + lane, v2 = f / 5, m2 = f - 5 * v2;
            float b2 = 0.f;
#pragma unroll 8
            for (int u = 0; u < 32; ++u) b2 = fmaf(xq[320 + u * 5 + m2], w_pre2[u * 16 + v2], b2);
            sh[wv][64 + f] = b2 * 0.17677669529663687f;
        }
    }
    __syncthreads();

    // ---- G[e] = b2p[e] + hid . W2p[:, e]  (lane covers e, e+64, 128+(e&15)) ----
    {
        const int e2 = 128 + (lane & 15);
        float g0 = b2p[lane], g1 = b2p[64 + lane], g2 = b2p[e2];
        for (int k = 0; k < 64; ++k) {
            float hk = shid[wv][k];
            const float* wrow = w2p + k * 144;
            g0 = fmaf(hk, wrow[lane], g0);
            g1 = fmaf(hk, wrow[64 + lane], g1);
            g2 = fmaf(hk, wrow[e2], g2);
        }
        sG[wv][lane] = g0;
        sG[wv][64 + lane] = g1;
        if (lane < 16) sG[wv][128 + lane] = g2;
    }
    __syncthreads();

    // ---- tensor product, lane u = 0..15; (1,1,1) & (2,2,1) vanish (antisym) ----
    float y0 = 0.f, z0 = 0.f, z1 = 0.f, z2 = 0.f, z3 = 0.f, z4 = 0.f;
    if (lane < 16) {
        const int u = lane;
        const float h0 = sh[wv][u];
        const float p0 = sh[wv][16 + 3 * u + 0];
        const float p1 = sh[wv][16 + 3 * u + 1];
        const float p2 = sh[wv][16 + 3 * u + 2];
        const float q0 = sh[wv][64 + 5 * u + 0];
        const float q1 = sh[wv][64 + 5 * u + 1];
        const float q2 = sh[wv][64 + 5 * u + 2];
        const float q3 = sh[wv][64 + 5 * u + 3];
        const float q4 = sh[wv][64 + 5 * u + 4];
        const float G0 = sG[wv][u],      G1 = sG[wv][16 + u], G2 = sG[wv][32 + u];
        const float G4 = sG[wv][64 + u], G5 = sG[wv][80 + u], G6 = sG[wv][96 + u];
        const float G8 = sG[wv][128 + u];

        // (0,0,0) -> lo0 : CG = 1
        y0 += G0 * h0 * h0;
        // (1,1,0) -> lo0 : CG = delta/sqrt(3)
        y0 += G2 * 0.5773502691896258f * (p0 * p0 + p1 * p1 + p2 * p2);
        // (2,2,0) -> lo0 : CG = delta/sqrt(5)
        y0 += G6 * 0.4472135954999579f * (q0 * q0 + q1 * q1 + q2 * q2 + q3 * q3 + q4 * q4);
        // (0,2,2) + (2,0,2) -> lo2 : CG = delta/sqrt(5)
        {
            float c15 = 0.4472135954999579f * h0 * (G1 + G5);
            z0 = fmaf(c15, q0, z0); z1 = fmaf(c15, q1, z1); z2 = fmaf(c15, q2, z2);
            z3 = fmaf(c15, q3, z3); z4 = fmaf(c15, q4, z4);
        }
        // (1,1,2) -> lo2
        {
            const float Ca = 0.31622776601683794f;  // 1/sqrt(10)
            const float Cb = 0.18257418583505536f;  // 1/sqrt(30)
            z0 = fmaf(G4, 2.f * Ca * p0 * p2, z0);
            z1 = fmaf(G4, 2.f * Ca * p0 * p1, z1);
            z2 = fmaf(G4, Cb * (2.f * p1 * p1 - p0 * p0 - p2 * p2), z2);
            z3 = fmaf(G4, 2.f * Ca * p2 * p1, z3);
            z4 = fmaf(G4, Ca * (p2 * p2 - p0 * p0), z4);
        }
        // (2,2,2) -> lo2
        {
            const float A2 = 0.2390457218668787f;   // sqrt(2/35)
            const float B2 = 0.20701966780270626f;  // sqrt(3/70)
            const float D2 = 0.11952286093343936f;  // sqrt(1/70)
            z0 = fmaf(G8, -2.f * A2 * q0 * q2 + 2.f * B2 * q1 * q3, z0);
            z1 = fmaf(G8,  2.f * B2 * (q0 * q3 - q4 * q1) + 2.f * D2 * q1 * q2, z1);
            z2 = fmaf(G8,  A2 * (q2 * q2 - q0 * q0 - q4 * q4) + D2 * (q1 * q1 + q3 * q3), z2);
            z3 = fmaf(G8,  2.f * B2 * (q0 * q1 + q3 * q4) + 2.f * D2 * q2 * q3, z3);
            z4 = fmaf(G8, -2.f * A2 * q2 * q4 + B2 * (q3 * q3 - q1 * q1), z4);
        }
    }

    // ---- reduce over the 16 u-lanes (butterfly; lanes>=16 carry zeros) ----
#pragma unroll
    for (int m = 1; m <= 8; m <<= 1) {
        y0 += __shfl_xor(y0, m, 64);
        z0 += __shfl_xor(z0, m, 64);
        z1 += __shfl_xor(z1, m, 64);
        z2 += __shfl_xor(z2, m, 64);
        z3 += __shfl_xor(z3, m, 64);
        z4 += __shfl_xor(z4, m, 64);
    }

    // ---- QF transform + [2,0,1] permutation; result is symmetric 3x3 ----
    if (lane == 0) {
        const float is3 = 0.5773502691896258f;  // 1/sqrt(3)
        const float is6 = 0.4082482904638631f;  // 1/sqrt(6)
        const float is2 = 0.7071067811865476f;  // 1/sqrt(2)
        float c0 = y0 * is3 - z2 * is6 - z4 * is2;
        float c4 = y0 * is3 + 2.f * z2 * is6;
        float c8 = y0 * is3 - z2 * is6 + z4 * is2;
        float c1 = z1 * is2;   // == c3
        float c2 = z0 * is2;   // == c6
        float c5 = z3 * is2;   // == c7
        float* o = out + (size_t)n * 9;
        o[0] = c8; o[1] = c2; o[2] = c5;
        o[3] = c2; o[4] = c0; o[5] = c1;
        o[6] = c5; o[7] = c1; o[8] = c4;
    }
}

extern "C" void kernel_launch(void* const* d_in, const int* in_sizes, int n_in,
                              void* d_out, int out_size, void* d_ws, size_t ws_size,
                              hipStream_t stream) {
    const float* x_scalar = (const float*)d_in[0];
    const float* x_sph    = (const float*)d_in[1];
    const float* w_pre0   = (const float*)d_in[2];
    const float* w_pre1   = (const float*)d_in[3];
    const float* w_pre2   = (const float*)d_in[4];
    const float* gw1      = (const float*)d_in[5];
    const float* gb1      = (const float*)d_in[6];
    const float* gw2      = (const float*)d_in[7];
    const float* gb2      = (const float*)d_in[8];
    const float* wpost0   = (const float*)d_in[9];
    const float* wpost1   = (const float*)d_in[10];
    const float* wpost2   = (const float*)d_in[11];

    float* w2p = (float*)d_ws;          // 64*144 floats
    float* b2p = w2p + 64 * 144;        // 144 floats

    setup_kernel<<<36, 256, 0, stream>>>(gw2, gb2, wpost0, wpost1, wpost2, w2p, b2p);
    csc_kernel<<<NA / 4, 256, 0, stream>>>(x_scalar, x_sph, w_pre0, w_pre1, w_pre2,
                                           gw1, gb1, w2p, b2p, (float*)d_out);
}

// Round 2
// 157.629 us; speedup vs baseline: 1.7579x; 1.7579x over previous
//
#include <hip/hip_runtime.h>
#include <math.h>

#define NA 32768
#define ATW 4   // atoms per wave

// ---------------------------------------------------------------------------
// Setup kernel: fold wpost + scales into gw2/gb2.
//   W2p[k, e] = sum_w gw2[k, idx, u, w] * wpost_{lo(idx)}[pos(idx)*16 + w] * scale_lo
// ---------------------------------------------------------------------------
__global__ void setup_kernel(const float* __restrict__ gw2, const float* __restrict__ gb2,
                             const float* __restrict__ wpost0, const float* __restrict__ wpost1,
                             const float* __restrict__ wpost2,
                             float* __restrict__ w2p, float* __restrict__ b2p) {
    const int LO[9]  = {0, 2, 0, 1, 2, 2, 0, 1, 2};
    const int POS[9] = {0, 0, 1, 0, 1, 2, 2, 1, 3};
    const float SCALE[3] = {0.036084391824351615f,   // 1/(4*sqrt(48))
                            0.04419417382415922f,    // 1/(4*sqrt(32))
                            0.03125f};               // 1/(4*sqrt(64))
    int t = blockIdx.x * 256 + threadIdx.x;
    if (t >= 64 * 144) return;
    int e = t % 144, k = t / 144;
    int idx = e >> 4, u = e & 15;
    int lo = LO[idx], pos = POS[idx];
    const float* wp = (lo == 0) ? wpost0 : (lo == 1) ? wpost1 : wpost2;
    const float* wv = wp + pos * 16;
    float scale = SCALE[lo];

    const float* gsrc = gw2 + (size_t)k * 2304 + idx * 256 + u * 16;
    float s = 0.f;
#pragma unroll
    for (int w = 0; w < 16; ++w) s = fmaf(gsrc[w], wv[w], s);
    w2p[t] = s * scale;

    if (t < 144) {  // k == 0 here; same (idx,u,wv)
        const float* bsrc = gb2 + idx * 256 + u * 16;
        float sb = 0.f;
#pragma unroll
        for (int w = 0; w < 16; ++w) sb = fmaf(bsrc[w], wv[w], sb);
        b2p[t] = sb * scale;
    }
}

// ---------------------------------------------------------------------------
// Main kernel: 4 waves / block, ATW=4 atoms per wave (16 atoms / block).
// All LDS tiles are wave-private; barriers separate write->read phases.
// ---------------------------------------------------------------------------
__global__ __launch_bounds__(256) void csc_kernel(
    const float* __restrict__ x_scalar, const float* __restrict__ x_sph,
    const float* __restrict__ w_pre0, const float* __restrict__ w_pre1,
    const float* __restrict__ w_pre2,
    const float* __restrict__ gw1, const float* __restrict__ gb1,
    const float* __restrict__ w2p, const float* __restrict__ b2p,
    float* __restrict__ out)
{
    __shared__ float sxs [4][ATW][128];
    __shared__ float shid[4][ATW][64];
    __shared__ float sh  [4][ATW][144];  // [0:16) h0 | [16:64) h1 (16+3v+m) | [64:144) h2 (64+5v+m)
    __shared__ float sG  [4][ATW][144];  // idx*16+u

    const int lane = threadIdx.x & 63;
    const int wv   = threadIdx.x >> 6;
    const int n0   = (blockIdx.x * 4 + wv) * ATW;

    // ---- stage x_scalar for 4 atoms (coalesced float2) ----
#pragma unroll
    for (int a = 0; a < ATW; ++a) {
        const float2 v = *(const float2*)(x_scalar + (size_t)(n0 + a) * 128 + lane * 2);
        *(float2*)&sxs[wv][a][lane * 2] = v;
    }
    __syncthreads();

    // ---- hid[k]=silu(xs . gw1[:,k] + gb1[k]); lane = k, 4 atoms ----
    {
        float acc[ATW];
        const float b = gb1[lane];
#pragma unroll
        for (int a = 0; a < ATW; ++a) acc[a] = b;
        for (int u = 0; u < 128; u += 4) {
            const float w0 = gw1[(u    ) * 64 + lane];
            const float w1 = gw1[(u + 1) * 64 + lane];
            const float w2 = gw1[(u + 2) * 64 + lane];
            const float w3 = gw1[(u + 3) * 64 + lane];
#pragma unroll
            for (int a = 0; a < ATW; ++a) {
                const float4 x = *(const float4*)&sxs[wv][a][u];
                acc[a] = fmaf(x.x, w0, acc[a]);
                acc[a] = fmaf(x.y, w1, acc[a]);
                acc[a] = fmaf(x.z, w2, acc[a]);
                acc[a] = fmaf(x.w, w3, acc[a]);
            }
        }
#pragma unroll
        for (int a = 0; a < ATW; ++a) {
            const float v = acc[a];
            shid[wv][a][lane] = v / (1.f + __expf(-v));
        }
    }

    // ---- h values: l0 over all lanes (4-way reduce), l1 on 48 lanes, l2 on 64+16 ----
    {
        // l0: lane = qu*16 + v ; each lane sums 32 of 128 u's
        const int v0 = lane & 15, qu = lane >> 4;
        float a0[ATW];
#pragma unroll
        for (int a = 0; a < ATW; ++a) a0[a] = 0.f;
        for (int u = qu * 32; u < qu * 32 + 32; ++u) {
            const float w = w_pre0[u * 16 + v0];
#pragma unroll
            for (int a = 0; a < ATW; ++a)
                a0[a] = fmaf(x_sph[(size_t)(n0 + a) * 480 + u], w, a0[a]);
        }
#pragma unroll
        for (int a = 0; a < ATW; ++a) {
            a0[a] += __shfl_xor(a0[a], 16, 64);
            a0[a] += __shfl_xor(a0[a], 32, 64);
        }
        if (qu == 0) {
#pragma unroll
            for (int a = 0; a < ATW; ++a)
                sh[wv][a][v0] = a0[a] * 0.08838834764831845f;     // 1/sqrt(128)
        }
    }
    if (lane < 48) {   // l1: lane = 3v+m
        const int v = lane / 3, m = lane - 3 * v;
        float a1[ATW];
#pragma unroll
        for (int a = 0; a < ATW; ++a) a1[a] = 0.f;
        for (int u = 0; u < 64; ++u) {
            const float w = w_pre1[u * 16 + v];
#pragma unroll
            for (int a = 0; a < ATW; ++a)
                a1[a] = fmaf(x_sph[(size_t)(n0 + a) * 480 + 128 + u * 3 + m], w, a1[a]);
        }
#pragma unroll
        for (int a = 0; a < ATW; ++a) sh[wv][a][16 + lane] = a1[a] * 0.125f;  // 1/sqrt(64)
    }
    {   // l2: slot f = 5v+m ; lane does f=lane, lanes<16 also f=64+lane
        const int v = lane / 5, m = lane - 5 * v;
        float a2[ATW];
#pragma unroll
        for (int a = 0; a < ATW; ++a) a2[a] = 0.f;
        for (int u = 0; u < 32; ++u) {
            const float w = w_pre2[u * 16 + v];
#pragma unroll
            for (int a = 0; a < ATW; ++a)
                a2[a] = fmaf(x_sph[(size_t)(n0 + a) * 480 + 320 + u * 5 + m], w, a2[a]);
        }
#pragma unroll
        for (int a = 0; a < ATW; ++a) sh[wv][a][64 + lane] = a2[a] * 0.17677669529663687f;
        if (lane < 16) {
            const int f = 64 + lane, v2 = f / 5, m2 = f - 5 * v2;
            float b2a[ATW];
#pragma unroll
            for (int a = 0; a < ATW; ++a) b2a[a] = 0.f;
            for (int u = 0; u < 32; ++u) {
                const float w = w_pre2[u * 16 + v2];
#pragma unroll
                for (int a = 0; a < ATW; ++a)
                    b2a[a] = fmaf(x_sph[(size_t)(n0 + a) * 480 + 320 + u * 5 + m2], w, b2a[a]);
            }
#pragma unroll
            for (int a = 0; a < ATW; ++a) sh[wv][a][64 + f] = b2a[a] * 0.17677669529663687f;
        }
    }
    __syncthreads();

    // ---- G[e] = b2p[e] + hid . W2p[:, e] ; lane covers e, 64+e, 128+(e&15), 4 atoms ----
    {
        const int e2 = 128 + (lane & 15);
        const float bb0 = b2p[lane], bb1 = b2p[64 + lane], bb2 = b2p[e2];
        float g0[ATW], g1[ATW], g2[ATW];
#pragma unroll
        for (int a = 0; a < ATW; ++a) { g0[a] = bb0; g1[a] = bb1; g2[a] = bb2; }
        for (int k = 0; k < 64; k += 2) {
            const float* wr0 = w2p + (size_t)k * 144;
            const float* wr1 = wr0 + 144;
            const float wa0 = wr0[lane], wa1 = wr0[64 + lane], wa2 = wr0[e2];
            const float wb0 = wr1[lane], wb1 = wr1[64 + lane], wb2 = wr1[e2];
#pragma unroll
            for (int a = 0; a < ATW; ++a) {
                const float2 hk = *(const float2*)&shid[wv][a][k];
                g0[a] = fmaf(hk.x, wa0, g0[a]); g0[a] = fmaf(hk.y, wb0, g0[a]);
                g1[a] = fmaf(hk.x, wa1, g1[a]); g1[a] = fmaf(hk.y, wb1, g1[a]);
                g2[a] = fmaf(hk.x, wa2, g2[a]); g2[a] = fmaf(hk.y, wb2, g2[a]);
            }
        }
#pragma unroll
        for (int a = 0; a < ATW; ++a) {
            sG[wv][a][lane] = g0[a];
            sG[wv][a][64 + lane] = g1[a];
            if (lane < 16) sG[wv][a][128 + lane] = g2[a];
        }
    }
    __syncthreads();

    // ---- tensor product: lane = a*16 + u, all 64 lanes active ----
    {
        const int a = lane >> 4, u = lane & 15;
        const float h0 = sh[wv][a][u];
        const float p0 = sh[wv][a][16 + 3 * u + 0];
        const float p1 = sh[wv][a][16 + 3 * u + 1];
        const float p2 = sh[wv][a][16 + 3 * u + 2];
        const float q0 = sh[wv][a][64 + 5 * u + 0];
        const float q1 = sh[wv][a][64 + 5 * u + 1];
        const float q2 = sh[wv][a][64 + 5 * u + 2];
        const float q3 = sh[wv][a][64 + 5 * u + 3];
        const float q4 = sh[wv][a][64 + 5 * u + 4];
        const float G0 = sG[wv][a][u],      G1 = sG[wv][a][16 + u], G2 = sG[wv][a][32 + u];
        const float G4 = sG[wv][a][64 + u], G5 = sG[wv][a][80 + u], G6 = sG[wv][a][96 + u];
        const float G8 = sG[wv][a][128 + u];

        float y0 = 0.f, z0 = 0.f, z1 = 0.f, z2 = 0.f, z3 = 0.f, z4 = 0.f;
        // (0,0,0), (1,1,0), (2,2,0) -> lo0
        y0 += G0 * h0 * h0;
        y0 += G2 * 0.5773502691896258f * (p0 * p0 + p1 * p1 + p2 * p2);
        y0 += G6 * 0.4472135954999579f * (q0 * q0 + q1 * q1 + q2 * q2 + q3 * q3 + q4 * q4);
        // (0,2,2)+(2,0,2) -> lo2
        {
            const float c15 = 0.4472135954999579f * h0 * (G1 + G5);
            z0 = fmaf(c15, q0, z0); z1 = fmaf(c15, q1, z1); z2 = fmaf(c15, q2, z2);
            z3 = fmaf(c15, q3, z3); z4 = fmaf(c15, q4, z4);
        }
        // (1,1,2) -> lo2
        {
            const float Ca = 0.31622776601683794f;  // 1/sqrt(10)
            const float Cb = 0.18257418583505536f;  // 1/sqrt(30)
            z0 = fmaf(G4, 2.f * Ca * p0 * p2, z0);
            z1 = fmaf(G4, 2.f * Ca * p0 * p1, z1);
            z2 = fmaf(G4, Cb * (2.f * p1 * p1 - p0 * p0 - p2 * p2), z2);
            z3 = fmaf(G4, 2.f * Ca * p2 * p1, z3);
            z4 = fmaf(G4, Ca * (p2 * p2 - p0 * p0), z4);
        }
        // (2,2,2) -> lo2
        {
            const float A2 = 0.2390457218668787f;   // sqrt(2/35)
            const float B2 = 0.20701966780270626f;  // sqrt(3/70)
            const float D2 = 0.11952286093343936f;  // sqrt(1/70)
            z0 = fmaf(G8, -2.f * A2 * q0 * q2 + 2.f * B2 * q1 * q3, z0);
            z1 = fmaf(G8,  2.f * B2 * (q0 * q3 - q4 * q1) + 2.f * D2 * q1 * q2, z1);
            z2 = fmaf(G8,  A2 * (q2 * q2 - q0 * q0 - q4 * q4) + D2 * (q1 * q1 + q3 * q3), z2);
            z3 = fmaf(G8,  2.f * B2 * (q0 * q1 + q3 * q4) + 2.f * D2 * q2 * q3, z3);
            z4 = fmaf(G8, -2.f * A2 * q2 * q4 + B2 * (q3 * q3 - q1 * q1), z4);
        }

        // reduce over u within each 16-lane group
#pragma unroll
        for (int m = 1; m <= 8; m <<= 1) {
            y0 += __shfl_xor(y0, m, 64);
            z0 += __shfl_xor(z0, m, 64);
            z1 += __shfl_xor(z1, m, 64);
            z2 += __shfl_xor(z2, m, 64);
            z3 += __shfl_xor(z3, m, 64);
            z4 += __shfl_xor(z4, m, 64);
        }

        if (u == 0) {  // 4 lanes, one per atom
            const float is3 = 0.5773502691896258f;  // 1/sqrt(3)
            const float is6 = 0.4082482904638631f;  // 1/sqrt(6)
            const float is2 = 0.7071067811865476f;  // 1/sqrt(2)
            const float c0 = y0 * is3 - z2 * is6 - z4 * is2;
            const float c4 = y0 * is3 + 2.f * z2 * is6;
            const float c8 = y0 * is3 - z2 * is6 + z4 * is2;
            const float c1 = z1 * is2;
            const float c2 = z0 * is2;
            const float c5 = z3 * is2;
            float* o = out + (size_t)(n0 + a) * 9;
            o[0] = c8; o[1] = c2; o[2] = c5;
            o[3] = c2; o[4] = c0; o[5] = c1;
            o[6] = c5; o[7] = c1; o[8] = c4;
        }
    }
}

extern "C" void kernel_launch(void* const* d_in, const int* in_sizes, int n_in,
                              void* d_out, int out_size, void* d_ws, size_t ws_size,
                              hipStream_t stream) {
    const float* x_scalar = (const float*)d_in[0];
    const float* x_sph    = (const float*)d_in[1];
    const float* w_pre0   = (const float*)d_in[2];
    const float* w_pre1   = (const float*)d_in[3];
    const float* w_pre2   = (const float*)d_in[4];
    const float* gw1      = (const float*)d_in[5];
    const float* gb1      = (const float*)d_in[6];
    const float* gw2      = (const float*)d_in[7];
    const float* gb2      = (const float*)d_in[8];
    const float* wpost0   = (const float*)d_in[9];
    const float* wpost1   = (const float*)d_in[10];
    const float* wpost2   = (const float*)d_in[11];

    float* w2p = (float*)d_ws;          // 64*144 floats
    float* b2p = w2p + 64 * 144;        // 144 floats

    setup_kernel<<<36, 256, 0, stream>>>(gw2, gb2, wpost0, wpost1, wpost2, w2p, b2p);
    csc_kernel<<<NA / (4 * ATW), 256, 0, stream>>>(x_scalar, x_sph, w_pre0, w_pre1, w_pre2,
                                                   gw1, gb1, w2p, b2p, (float*)d_out);
}

// Round 3
// 27.558 us; speedup vs baseline: 10.0552x; 5.7200x over previous
//
#include <hip/hip_runtime.h>

#define NA 32768

typedef float  f32x4  __attribute__((ext_vector_type(4)));
typedef __bf16 bf16x8 __attribute__((ext_vector_type(8)));
typedef unsigned short u16x8 __attribute__((ext_vector_type(8)));
typedef unsigned short u16x4 __attribute__((ext_vector_type(4)));

// ws layout (unsigned short offsets):
//   [0,8192)      fragB_gw1  [ct4][kt4][lane64][8]
//   [8192,17408)  fragB_w2p  [ct9][kt2][lane64][8]   (wpost+scale folded)
//   [17408,19456) fragB_w0   [kt4][lane64][8]        (x 1/sqrt(128))
//   [19456,20480) fragB_w1   [kt2][lane64][8]        (x 1/sqrt(64))
//   [20480,20992) fragB_w2   [kt1][lane64][8]        (x 1/sqrt(32))
//   byte 41984:   b2p[144] fp32

__device__ __forceinline__ unsigned short bf16u(float f) {
    unsigned int x = __float_as_uint(f);
    x += 0x7FFFu + ((x >> 16) & 1u);          // round-to-nearest-even
    return (unsigned short)(x >> 16);
}

__device__ __forceinline__ f32x4 MFMA16(u16x8 a, u16x8 b, f32x4 c) {
    return __builtin_amdgcn_mfma_f32_16x16x32_bf16(
        __builtin_bit_cast(bf16x8, a), __builtin_bit_cast(bf16x8, b), c, 0, 0, 0);
}

__global__ void setup_kernel(const float* __restrict__ gw1,
                             const float* __restrict__ gw2, const float* __restrict__ gb2,
                             const float* __restrict__ w_pre0, const float* __restrict__ w_pre1,
                             const float* __restrict__ w_pre2,
                             const float* __restrict__ wpost0, const float* __restrict__ wpost1,
                             const float* __restrict__ wpost2,
                             unsigned short* __restrict__ wsS, float* __restrict__ b2p)
{
    const int t = blockIdx.x * 256 + threadIdx.x;
    const int LO[9]  = {0,2,0,1,2,2,0,1,2};
    const int POS[9] = {0,0,1,0,1,2,2,1,3};
    const float SCALE[3] = {0.036084391824351615f,   // 1/(4*sqrt(48))
                            0.04419417382415922f,    // 1/(4*sqrt(32))
                            0.03125f};               // 1/(4*sqrt(64))
    if (t < 8192) {                      // gw1 B-frags
        const int j = t & 7, lane = (t >> 3) & 63, kt = (t >> 9) & 3, ct = t >> 11;
        const int k = kt * 32 + ((lane >> 4) & 3) * 8 + j;
        const int n = ct * 16 + (lane & 15);
        wsS[t] = bf16u(gw1[k * 64 + n]);
    } else if (t < 17408) {              // W2p B-frags (fold wpost+scale)
        const int q = t - 8192;
        const int j = q & 7, lane = (q >> 3) & 63, kt = (q >> 9) & 1, ct = q >> 10;
        const int k = kt * 32 + ((lane >> 4) & 3) * 8 + j;
        const int idx = ct, u = lane & 15;
        const int lo = LO[idx];
        const float* wp = (lo == 0) ? wpost0 : (lo == 1) ? wpost1 : wpost2;
        const float* wv = wp + POS[idx] * 16;
        const float* gsrc = gw2 + (size_t)k * 2304 + idx * 256 + u * 16;
        float s = 0.f;
        for (int w = 0; w < 16; ++w) s = fmaf(gsrc[w], wv[w], s);
        wsS[8192 + q] = bf16u(s * SCALE[lo]);
    } else if (t < 19456) {              // w_pre0 B-frags
        const int q = t - 17408;
        const int j = q & 7, lane = (q >> 3) & 63, kt = q >> 9;
        const int k = kt * 32 + ((lane >> 4) & 3) * 8 + j;
        wsS[17408 + q] = bf16u(w_pre0[k * 16 + (lane & 15)] * 0.08838834764831845f);
    } else if (t < 20480) {              // w_pre1 B-frags
        const int q = t - 19456;
        const int j = q & 7, lane = (q >> 3) & 63, kt = q >> 9;
        const int k = kt * 32 + ((lane >> 4) & 3) * 8 + j;
        wsS[19456 + q] = bf16u(w_pre1[k * 16 + (lane & 15)] * 0.125f);
    } else if (t < 20992) {              // w_pre2 B-frags
        const int q = t - 20480;
        const int j = q & 7, lane = (q >> 3) & 63;
        const int k = ((lane >> 4) & 3) * 8 + j;
        wsS[20480 + q] = bf16u(w_pre2[k * 16 + (lane & 15)] * 0.17677669529663687f);
    } else if (t < 21136) {              // b2p (fp32)
        const int e = t - 20992;
        const int idx = e >> 4, u = e & 15;
        const int lo = LO[idx];
        const float* wp = (lo == 0) ? wpost0 : (lo == 1) ? wpost1 : wpost2;
        const float* wv = wp + POS[idx] * 16;
        const float* bsrc = gb2 + idx * 256 + u * 16;
        float sb = 0.f;
        for (int w = 0; w < 16; ++w) sb = fmaf(bsrc[w], wv[w], sb);
        b2p[e] = sb * SCALE[lo];
    }
}

// ---------------------------------------------------------------------------
// One wave = 16 atoms. 4 waves/block, wave-private LDS, no barriers.
// ---------------------------------------------------------------------------
__global__ __launch_bounds__(256) void csc_kernel(
    const float* __restrict__ x_scalar, const float* __restrict__ x_sph,
    const float* __restrict__ gb1,
    const unsigned short* __restrict__ wsS, const float* __restrict__ b2p,
    float* __restrict__ out)
{
    __shared__ __align__(16) unsigned short sSph[4][16][356]; // bf16 x_sph[128:480], pad->356
    __shared__ __align__(16) unsigned short sH[4][16][72];    // bf16 H tile, row stride 72

    const int lane = threadIdx.x & 63;
    const int wvi  = threadIdx.x >> 6;
    const int lm = lane & 15, lg = lane >> 4;
    const int n0 = (blockIdx.x * 4 + wvi) * 16;

    // ---------- stage x_sph[:,128:480] -> LDS bf16 (coalesced float4) ----------
    {
        const int a = lane >> 2, qd = lane & 3;
        const float* __restrict__ src = x_sph + (size_t)(n0 + a) * 480 + 128;
        unsigned short* dst = &sSph[wvi][a][0];
#pragma unroll
        for (int c = 0; c < 22; ++c) {
            const int i4 = qd + 4 * c;
            const float4 v = *(const float4*)(src + i4 * 4);
            u16x4 w = { bf16u(v.x), bf16u(v.y), bf16u(v.z), bf16u(v.w) };
            *(u16x4*)(dst + i4 * 4) = w;
        }
    }

    // ---------- Phase A: H = silu(Xs @ gw1 + gb1) ----------
    f32x4 accA0, accA1, accA2, accA3;
    {
        const float b0 = gb1[lm], b1 = gb1[16 + lm], bv2 = gb1[32 + lm], b3 = gb1[48 + lm];
        accA0 = (f32x4){b0,b0,b0,b0}; accA1 = (f32x4){b1,b1,b1,b1};
        accA2 = (f32x4){bv2,bv2,bv2,bv2}; accA3 = (f32x4){b3,b3,b3,b3};
    }
#pragma unroll
    for (int kt = 0; kt < 4; ++kt) {
        const float* xr = x_scalar + (size_t)(n0 + lm) * 128 + kt * 32 + lg * 8;
        const float4 xa = *(const float4*)xr;
        const float4 xb = *(const float4*)(xr + 4);
        const u16x8 af = { bf16u(xa.x), bf16u(xa.y), bf16u(xa.z), bf16u(xa.w),
                           bf16u(xb.x), bf16u(xb.y), bf16u(xb.z), bf16u(xb.w) };
        accA0 = MFMA16(af, *(const u16x8*)(wsS + (size_t)((0*4+kt)*64+lane)*8), accA0);
        accA1 = MFMA16(af, *(const u16x8*)(wsS + (size_t)((1*4+kt)*64+lane)*8), accA1);
        accA2 = MFMA16(af, *(const u16x8*)(wsS + (size_t)((2*4+kt)*64+lane)*8), accA2);
        accA3 = MFMA16(af, *(const u16x8*)(wsS + (size_t)((3*4+kt)*64+lane)*8), accA3);
    }
#pragma unroll
    for (int r = 0; r < 4; ++r) {   // silu -> sH  (atom=(lg*4+r), col=ct*16+lm)
        const int atom = lg * 4 + r;
        const float v0 = accA0[r], v1 = accA1[r], v2 = accA2[r], v3 = accA3[r];
        sH[wvi][atom][ 0 + lm] = bf16u(v0 / (1.f + __expf(-v0)));
        sH[wvi][atom][16 + lm] = bf16u(v1 / (1.f + __expf(-v1)));
        sH[wvi][atom][32 + lm] = bf16u(v2 / (1.f + __expf(-v2)));
        sH[wvi][atom][48 + lm] = bf16u(v3 / (1.f + __expf(-v3)));
    }

    // ---------- Phase B: G = b2p + H @ W2p (skip antisym ct 3,7) ----------
    const u16x8 hf0 = *(const u16x8*)&sH[wvi][lm][lg * 8];
    const u16x8 hf1 = *(const u16x8*)&sH[wvi][lm][32 + lg * 8];
    f32x4 gB0, gB1, gB2, gB4, gB5, gB6, gB8;
#define INITB(ACC, CT) { const float b = b2p[(CT)*16 + lm]; ACC = (f32x4){b,b,b,b}; }
    INITB(gB0,0) INITB(gB1,1) INITB(gB2,2) INITB(gB4,4) INITB(gB5,5) INITB(gB6,6) INITB(gB8,8)
#define DOB(ACC, CT) \
    ACC = MFMA16(hf0, *(const u16x8*)(wsS + 8192 + (size_t)(((CT)*2+0)*64+lane)*8), ACC); \
    ACC = MFMA16(hf1, *(const u16x8*)(wsS + 8192 + (size_t)(((CT)*2+1)*64+lane)*8), ACC);
    DOB(gB0,0) DOB(gB1,1) DOB(gB2,2) DOB(gB4,4) DOB(gB5,5) DOB(gB6,6) DOB(gB8,8)

    // ---------- Phase C: pre-linears ----------
    f32x4 acc0 = (f32x4){0.f,0.f,0.f,0.f};          // l0
#pragma unroll
    for (int kt = 0; kt < 4; ++kt) {
        const float* xr = x_sph + (size_t)(n0 + lm) * 480 + kt * 32 + lg * 8;
        const float4 xa = *(const float4*)xr;
        const float4 xb = *(const float4*)(xr + 4);
        const u16x8 af = { bf16u(xa.x), bf16u(xa.y), bf16u(xa.z), bf16u(xa.w),
                           bf16u(xb.x), bf16u(xb.y), bf16u(xb.z), bf16u(xb.w) };
        acc0 = MFMA16(af, *(const u16x8*)(wsS + 17408 + (size_t)(kt*64+lane)*8), acc0);
    }
    const unsigned short* sp1 = &sSph[wvi][lm][0];   // l1 gathers (stride 3)
    f32x4 accP[3];
#pragma unroll
    for (int m = 0; m < 3; ++m) {
        f32x4 acc = (f32x4){0.f,0.f,0.f,0.f};
#pragma unroll
        for (int kt = 0; kt < 2; ++kt) {
            const int base = 3 * (kt * 32 + lg * 8) + m;
            const u16x8 af = { sp1[base], sp1[base+3], sp1[base+6],  sp1[base+9],
                               sp1[base+12], sp1[base+15], sp1[base+18], sp1[base+21] };
            acc = MFMA16(af, *(const u16x8*)(wsS + 19456 + (size_t)(kt*64+lane)*8), acc);
        }
        accP[m] = acc;
    }
    const unsigned short* sp2 = &sSph[wvi][lm][192]; // l2 gathers (stride 5)
    f32x4 accQ[5];
#pragma unroll
    for (int m = 0; m < 5; ++m) {
        const int base = 5 * (lg * 8) + m;
        const u16x8 af = { sp2[base], sp2[base+5], sp2[base+10], sp2[base+15],
                           sp2[base+20], sp2[base+25], sp2[base+30], sp2[base+35] };
        accQ[m] = MFMA16(af, *(const u16x8*)(wsS + 20480 + (size_t)lane*8),
                         (f32x4){0.f,0.f,0.f,0.f});
    }

    // ---------- TP epilogue: all operands already in the right lanes ----------
    const float C110 = 0.5773502691896258f;
    const float C220 = 0.4472135954999579f;
    const float Ca = 0.31622776601683794f, Cb = 0.18257418583505536f;
    const float A2 = 0.2390457218668787f, B2c = 0.20701966780270626f, D2 = 0.11952286093343936f;
    const float is3 = 0.5773502691896258f, is6 = 0.4082482904638631f, is2 = 0.7071067811865476f;

#pragma unroll
    for (int r = 0; r < 4; ++r) {
        const float h0 = acc0[r];
        const float p0 = accP[0][r], p1 = accP[1][r], p2 = accP[2][r];
        const float q0 = accQ[0][r], q1 = accQ[1][r], q2 = accQ[2][r],
                    q3 = accQ[3][r], q4 = accQ[4][r];
        const float G0 = gB0[r], G1 = gB1[r], G2 = gB2[r], G4 = gB4[r],
                    G5 = gB5[r], G6 = gB6[r], G8 = gB8[r];

        float y0 = G0 * h0 * h0
                 + G2 * C110 * (p0*p0 + p1*p1 + p2*p2)
                 + G6 * C220 * (q0*q0 + q1*q1 + q2*q2 + q3*q3 + q4*q4);
        float z0, z1, z2, z3, z4;
        {
            const float c15 = C220 * h0 * (G1 + G5);
            z0 = c15 * q0; z1 = c15 * q1; z2 = c15 * q2; z3 = c15 * q3; z4 = c15 * q4;
        }
        z0 = fmaf(G4, 2.f*Ca*p0*p2, z0);
        z1 = fmaf(G4, 2.f*Ca*p0*p1, z1);
        z2 = fmaf(G4, Cb*(2.f*p1*p1 - p0*p0 - p2*p2), z2);
        z3 = fmaf(G4, 2.f*Ca*p2*p1, z3);
        z4 = fmaf(G4, Ca*(p2*p2 - p0*p0), z4);
        z0 = fmaf(G8, -2.f*A2*q0*q2 + 2.f*B2c*q1*q3, z0);
        z1 = fmaf(G8,  2.f*B2c*(q0*q3 - q4*q1) + 2.f*D2*q1*q2, z1);
        z2 = fmaf(G8,  A2*(q2*q2 - q0*q0 - q4*q4) + D2*(q1*q1 + q3*q3), z2);
        z3 = fmaf(G8,  2.f*B2c*(q0*q1 + q3*q4) + 2.f*D2*q2*q3, z3);
        z4 = fmaf(G8, -2.f*A2*q2*q4 + B2c*(q3*q3 - q1*q1), z4);

#pragma unroll
        for (int msk = 1; msk <= 8; msk <<= 1) {   // reduce over 16 u-lanes
            y0 += __shfl_xor(y0, msk, 64);
            z0 += __shfl_xor(z0, msk, 64);
            z1 += __shfl_xor(z1, msk, 64);
            z2 += __shfl_xor(z2, msk, 64);
            z3 += __shfl_xor(z3, msk, 64);
            z4 += __shfl_xor(z4, msk, 64);
        }

        const float c0 = y0*is3 - z2*is6 - z4*is2;
        const float c4 = y0*is3 + 2.f*z2*is6;
        const float c8 = y0*is3 - z2*is6 + z4*is2;
        const float c1 = z1*is2, c2v = z0*is2, c5 = z3*is2;
        if (lm < 9) {
            const float val = (lm==0)?c8 : (lm==1)?c2v : (lm==2)?c5 : (lm==3)?c2v
                            : (lm==4)?c0 : (lm==5)?c1 : (lm==6)?c5 : (lm==7)?c1 : c4;
            out[(size_t)(n0 + lg*4 + r) * 9 + lm] = val;
        }
    }
}

extern "C" void kernel_launch(void* const* d_in, const int* in_sizes, int n_in,
                              void* d_out, int out_size, void* d_ws, size_t ws_size,
                              hipStream_t stream) {
    const float* x_scalar = (const float*)d_in[0];
    const float* x_sph    = (const float*)d_in[1];
    const float* w_pre0   = (const float*)d_in[2];
    const float* w_pre1   = (const float*)d_in[3];
    const float* w_pre2   = (const float*)d_in[4];
    const float* gw1      = (const float*)d_in[5];
    const float* gb1      = (const float*)d_in[6];
    const float* gw2      = (const float*)d_in[7];
    const float* gb2      = (const float*)d_in[8];
    const float* wpost0   = (const float*)d_in[9];
    const float* wpost1   = (const float*)d_in[10];
    const float* wpost2   = (const float*)d_in[11];

    unsigned short* wsS = (unsigned short*)d_ws;
    float* b2p = (float*)((char*)d_ws + 41984);

    setup_kernel<<<83, 256, 0, stream>>>(gw1, gw2, gb2, w_pre0, w_pre1, w_pre2,
                                         wpost0, wpost1, wpost2, wsS, b2p);
    csc_kernel<<<512, 256, 0, stream>>>(x_scalar, x_sph, gb1, wsS, b2p, (float*)d_out);
}